// Round 6
// baseline (203.320 us; speedup 1.0000x reference)
//
#include <hip/hip_runtime.h>

// MultiHeadAttentionForViTDiscriminator: B=4, C=1024, D=1024, H=16, DH=64
// R6: attn -> swapped-operand QK (St = mfma(K,Q)) on the PROVEN 16x16x32
//     intrinsic + K-row permutation in LDS so PV's A-frag assembles in-register
//     (no Ps LDS, no cross-lane ops). LDS 68->33KB => 4 blocks/CU.
//     GEMMs/cvt unchanged from R5.
// Workspace (48 MB):
//   [0,8M)  W16 (Wq,Wk,Wv,Wp f16, contiguous 4M f16)
//   [8,32M) X16: Xq16,Xk16,Xv16; Xq16 slot -> vT after qk-gemm,
//           Xk16 slot -> attn_out after vT-gemm
//   [32,40M) qb (pre-scaled by -2*C2)   [40,48M) kb
//   norms q2c2/k2c2 (2 x 256KB f32) live in d_out's head (dead before final GEMM).

typedef _Float16 f16;
typedef __attribute__((ext_vector_type(2))) _Float16 f16x2;
typedef __attribute__((ext_vector_type(8))) _Float16 f16x8;
typedef __attribute__((ext_vector_type(4))) float f32x4;

#define MFMA16(a, b, c) __builtin_amdgcn_mfma_f32_16x16x32_f16((a), (b), (c), 0, 0, 0)

constexpr double LOG2E = 1.4426950408889634;
constexpr double C2d = 0.015625 * LOG2E * LOG2E;  // (DH^-0.5 * log2e)^2

#if __has_builtin(__builtin_amdgcn_exp2f)
#define EXP2F(x) __builtin_amdgcn_exp2f(x)
#else
#define EXP2F(x) exp2f(x)
#endif
#if __has_builtin(__builtin_amdgcn_sqrtf)
#define SQRTF(x) __builtin_amdgcn_sqrtf(x)
#else
#define SQRTF(x) sqrtf(x)
#endif

// Async global->LDS, 16B per lane (dest = wave-uniform base + lane*16).
__device__ __forceinline__ void stage16(const f16* g, f16* lds_base_uniform) {
#if __has_builtin(__builtin_amdgcn_global_load_lds)
    __builtin_amdgcn_global_load_lds((const __attribute__((address_space(1))) void*)g,
                                     (__attribute__((address_space(3))) void*)lds_base_uniform,
                                     16, 0, 0);
#else
    const int lane = threadIdx.x & 63;
    *(f16x8*)(lds_base_uniform + lane * 8) = *(const f16x8*)g;
#endif
}

// One conversion kernel for all fp32->fp16 inputs. 8192 blocks x 2048 elems = 16M.
__global__ __launch_bounds__(256) void cvt_all(const float* __restrict__ Xq,
                                               const float* __restrict__ Xk,
                                               const float* __restrict__ Xv,
                                               const float* __restrict__ Wq,
                                               const float* __restrict__ Wk,
                                               const float* __restrict__ Wv,
                                               const float* __restrict__ Wp,
                                               f16* __restrict__ W16,
                                               f16* __restrict__ X16) {
    const size_t idx = (size_t)blockIdx.x * 2048 + threadIdx.x * 8;
    const size_t M4 = 4ull << 20, M1 = 1ull << 20;
    const float* s;
    f16* d;
    if (idx < 3 * M4) {  // X region (12M)
        if (idx < M4) s = Xq + idx;
        else if (idx < 2 * M4) s = Xk + (idx - M4);
        else s = Xv + (idx - 2 * M4);
        d = X16 + idx;
    } else {  // W region (4M)
        size_t wi = idx - 3 * M4;
        if (wi < M1) s = Wq + wi;
        else if (wi < 2 * M1) s = Wk + (wi - M1);
        else if (wi < 3 * M1) s = Wv + (wi - 2 * M1);
        else s = Wp + (wi - 3 * M1);
        d = W16 + wi;
    }
    float4 a = *(const float4*)s;
    float4 b = *(const float4*)(s + 4);
    f16x8 o;
    o[0] = (f16)a.x; o[1] = (f16)a.y; o[2] = (f16)a.z; o[3] = (f16)a.w;
    o[4] = (f16)b.x; o[5] = (f16)b.y; o[6] = (f16)b.z; o[7] = (f16)b.w;
    *(f16x8*)d = o;
}

// C[M,N] = (A[M,K] * Bw[N,K]^T) * osc.  BM=128 BN=64 BK=64; 4 waves, wave tile 32x64.
// NORMS: emit per-row head-norms from the ROUNDED stored values.
// F32OUT: f32 out + bias.  blockIdx.z offsets A/Bw/Co/nrm (fused q/k launch).
template <bool NORMS, bool F32OUT>
__global__ __launch_bounds__(256, 2) void gemm_bt(const f16* __restrict__ A,
                                                  const f16* __restrict__ Bw,
                                                  f16* __restrict__ Co,
                                                  float* __restrict__ Cf,
                                                  const float* __restrict__ bias,
                                                  float* __restrict__ nrm,
                                                  float osc0, float osc1,
                                                  float ns0, float ns1,
                                                  int M, int N, int K) {
    __shared__ __attribute__((aligned(16))) f16 As[128 * 64];
    __shared__ __attribute__((aligned(16))) f16 Bs[64 * 64];
    const int tid = threadIdx.x;
    const int lane = tid & 63;
    const int w = tid >> 6;
    const int l15 = lane & 15, l4 = lane >> 4;
    const int z = blockIdx.z;
    A += (size_t)z * (4u << 20);
    Bw += (size_t)z * (1u << 20);
    Co += (size_t)z * (4u << 20);
    if (NORMS) nrm += (size_t)z * 65536;
    const float osc = z ? osc1 : osc0;
    const float nscale = z ? ns1 : ns0;
    const int wr = w * 32;
    // bijective XCD swizzle (nwg multiple of 8)
    const int nwg = gridDim.x * gridDim.y;
    const int f = blockIdx.y * gridDim.x + blockIdx.x;
    const int g = (f & 7) * (nwg >> 3) + (f >> 3);
    const int row0 = (g / gridDim.x) * 128;
    const int col0 = (g % gridDim.x) * 64;

    const int sr8 = lane >> 3;
    const int sc8 = (lane & 7) * 8;
    f32x4 acc[2][4] = {};

    for (int kt = 0; kt < K; kt += 64) {
        __syncthreads();
#pragma unroll
        for (int t = 0; t < 4; ++t)
            stage16(&A[(size_t)(row0 + w * 32 + t * 8 + sr8) * K + kt + sc8], &As[(w * 32 + t * 8) * 64]);
#pragma unroll
        for (int t = 0; t < 2; ++t)
            stage16(&Bw[(size_t)(col0 + w * 16 + t * 8 + sr8) * K + kt + sc8], &Bs[(w * 16 + t * 8) * 64]);
        __syncthreads();
#pragma unroll
        for (int ks = 0; ks < 2; ++ks) {
            f16x8 af[2], bf[4];
#pragma unroll
            for (int m = 0; m < 2; ++m)
                af[m] = *(const f16x8*)&As[(wr + m * 16 + l15) * 64 + ks * 32 + l4 * 8];
#pragma unroll
            for (int n = 0; n < 4; ++n)
                bf[n] = *(const f16x8*)&Bs[(n * 16 + l15) * 64 + ks * 32 + l4 * 8];
#pragma unroll
            for (int m = 0; m < 2; ++m)
#pragma unroll
                for (int n = 0; n < 4; ++n) acc[m][n] = MFMA16(af[m], bf[n], acc[m][n]);
        }
    }

    if (NORMS) {
        const int h = col0 >> 6;
#pragma unroll
        for (int m = 0; m < 2; ++m)
#pragma unroll
            for (int r = 0; r < 4; ++r) {
                float s = 0.f;
#pragma unroll
                for (int n = 0; n < 4; ++n) {
                    float v = (float)(f16)(acc[m][n][r] * osc);
                    s += v * v;
                }
                s += __shfl_xor(s, 1);
                s += __shfl_xor(s, 2);
                s += __shfl_xor(s, 4);
                s += __shfl_xor(s, 8);
                if (l15 == 0) {
                    int row = row0 + wr + m * 16 + l4 * 4 + r;
                    nrm[(size_t)((row >> 10) * 16 + h) * 1024 + (row & 1023)] = s * nscale;
                }
            }
    }

#pragma unroll
    for (int m = 0; m < 2; ++m)
#pragma unroll
        for (int n = 0; n < 4; ++n)
#pragma unroll
            for (int r = 0; r < 4; ++r) {
                int rr = row0 + wr + m * 16 + l4 * 4 + r;
                int cc = col0 + n * 16 + l15;
                if (F32OUT)
                    Cf[(size_t)rr * N + cc] = acc[m][n][r] + bias[cc];
                else
                    Co[(size_t)rr * N + cc] = (f16)(acc[m][n][r] * osc);
            }
}

// Distance attention. grid (8,64): 128 q-rows/block, 4 waves x 32 rows.
// Swapped QK (A=K,B=Q) + permuted K slots => in-register P; no Ps LDS.
__global__ __launch_bounds__(256, 4) void attn(const f16* __restrict__ qs,
                                               const f16* __restrict__ kb,
                                               const f16* __restrict__ vT,
                                               const float* __restrict__ q2c2,
                                               const float* __restrict__ k2c2,
                                               f16* __restrict__ out) {
    __shared__ __attribute__((aligned(16))) f16 Ks[128 * 64];  // permuted slots + XOR swizzle
    __shared__ __attribute__((aligned(16))) f16 Vs[64 * 128];  // XOR-swizzled
    __shared__ float k2tile[128];                              // linear (keyed by true k)
    const int tid = threadIdx.x;
    const int lane = tid & 63;
    const int w = tid >> 6;
    const int l15 = lane & 15, l4 = lane >> 4;
    // XCD remap: 8 bh per XCD -> K/V slices L2-resident
    const int fid = blockIdx.y * 8 + blockIdx.x;
    const int qt = (fid >> 3) & 7;
    const int bh = (fid & 7) * 8 + (fid >> 6);
    const int b = bh >> 4, h = bh & 15;
    const int wq = w * 32;
    const int hcol = h * 64;
    const int qrow0 = b * 1024 + qt * 128;
    const f16* vTh = vT + (size_t)hcol * 4096 + b * 1024;  // vT[d=1024][tok=4096]

    const int sr = tid >> 3, sc0 = (tid & 7) * 8;   // K staging (keys sr+i*32)
    const int vr = tid >> 4, vc0 = (tid & 15) * 8;  // V staging (rows vr+j*16)
    const int vsw = (vr & 7) << 3;
    const int fsw = (l15 & 7) << 3;                 // fragment-read swizzle (slot-row&7 = l15&7)

    // Q frags as B-operand (rows wq+m*16+l15), pre-scaled by -2*C2
    f16x8 bq[2][2];
#pragma unroll
    for (int m = 0; m < 2; ++m)
#pragma unroll
        for (int ks = 0; ks < 2; ++ks)
            bq[m][ks] = *(const f16x8*)&qs[(size_t)(qrow0 + wq + m * 16 + l15) * 1024 + hcol + ks * 32 + l4 * 8];
    // q2*C2 at lane-local q (col index l15)
    float q2m[2];
#pragma unroll
    for (int m = 0; m < 2; ++m) q2m[m] = q2c2[(size_t)bh * 1024 + qt * 128 + wq + m * 16 + l15];

    f32x4 accv[2][4] = {};
    float den[2] = {0.f, 0.f};

    f16x8 kreg[4], vreg[4];
    float k2reg = 0.f;
#define ISSUE_LOADS(KT)                                                                                      \
    {                                                                                                        \
        _Pragma("unroll") for (int i = 0; i < 4; ++i)                                                        \
            kreg[i] = *(const f16x8*)&kb[(size_t)(b * 1024 + (KT) * 128 + sr + i * 32) * 1024 + hcol + sc0]; \
        _Pragma("unroll") for (int j = 0; j < 4; ++j)                                                        \
            vreg[j] = *(const f16x8*)&vTh[(size_t)(vr + j * 16) * 4096 + (KT) * 128 + vc0];                  \
        k2reg = (tid < 128) ? k2c2[(size_t)bh * 1024 + (KT) * 128 + tid] : 0.f;                              \
    }

    ISSUE_LOADS(0)

    for (int kt = 0; kt < 8; ++kt) {
        __syncthreads();  // prev-tile readers done
        // K staging with slot permutation: key kap -> slot s so that QK D-rows
        // deliver PV A-frag k-order. s = ((kap>>5)&3)*32+((kap>>2)&1)*16+((kap>>3)&3)*4+(kap&3)
#pragma unroll
        for (int i = 0; i < 4; ++i) {
            const int kap = sr + i * 32;
            const int s = ((kap >> 5) & 3) * 32 + ((kap >> 2) & 1) * 16 + ((kap >> 3) & 3) * 4 + (kap & 3);
            *(f16x8*)&Ks[s * 64 + (sc0 ^ ((s & 7) << 3))] = kreg[i];
        }
#pragma unroll
        for (int j = 0; j < 4; ++j) *(f16x8*)&Vs[(vr + j * 16) * 128 + (vc0 ^ vsw)] = vreg[j];
        if (tid < 128) k2tile[tid] = k2reg;
        __syncthreads();
        if (kt < 7) ISSUE_LOADS(kt + 1)  // prefetch hides under compute

#pragma unroll
        for (int kk = 0; kk < 4; ++kk) {
            // QK for windows n=2kk, 2kk+1; assemble PV A-frag dwords in-register
            unsigned um[2][4];
#pragma unroll
            for (int half = 0; half < 2; ++half) {
                const int n = kk * 2 + half;
                f16x8 kf0 = *(const f16x8*)&Ks[(n * 16 + l15) * 64 + ((l4 * 8) ^ fsw)];
                f16x8 kf1 = *(const f16x8*)&Ks[(n * 16 + l15) * 64 + ((32 + l4 * 8) ^ fsw)];
                // true keys at this lane's D-rows: kk*32 + l4*8 + half*4 + r
                f32x4 k2q = *(const f32x4*)&k2tile[kk * 32 + l4 * 8 + half * 4];
#pragma unroll
                for (int m = 0; m < 2; ++m) {
                    f32x4 c0;
#pragma unroll
                    for (int r = 0; r < 4; ++r) c0[r] = q2m[m] + k2q[r];
                    f32x4 st = MFMA16(kf0, bq[m][0], c0);
                    st = MFMA16(kf1, bq[m][1], st);
                    float p0 = EXP2F(SQRTF(fmaxf(st[0], 0.f)));
                    float p1 = EXP2F(SQRTF(fmaxf(st[1], 0.f)));
                    float p2 = EXP2F(SQRTF(fmaxf(st[2], 0.f)));
                    float p3 = EXP2F(SQRTF(fmaxf(st[3], 0.f)));
                    den[m] += (p0 + p1) + (p2 + p3);
                    f16x2 lo = {(f16)p0, (f16)p1};
                    f16x2 hi = {(f16)p2, (f16)p3};
                    um[m][half * 2] = __builtin_bit_cast(unsigned, lo);
                    um[m][half * 2 + 1] = __builtin_bit_cast(unsigned, hi);
                }
            }
            f16x8 ap[2];
#pragma unroll
            for (int m = 0; m < 2; ++m) {
                uint4 u = {um[m][0], um[m][1], um[m][2], um[m][3]};
                ap[m] = __builtin_bit_cast(f16x8, u);
            }
            // PV for this kk (B-operand: V^T rows = d = n2*16+l15)
#pragma unroll
            for (int n2 = 0; n2 < 4; ++n2) {
                f16x8 bv = *(const f16x8*)&Vs[(n2 * 16 + l15) * 128 + ((kk * 32 + l4 * 8) ^ fsw)];
#pragma unroll
                for (int m = 0; m < 2; ++m) accv[m][n2] = MFMA16(ap[m], bv, accv[m][n2]);
            }
        }
    }

    // den: reduce across l4 groups (q = wq+m*16+l15 fixed per lane per m)
    float iden[2];
#pragma unroll
    for (int m = 0; m < 2; ++m) {
        float d = den[m];
        d += __shfl_xor(d, 16);
        d += __shfl_xor(d, 32);
        iden[m] = 1.0f / d;
    }
#pragma unroll
    for (int m = 0; m < 2; ++m)
#pragma unroll
        for (int r = 0; r < 4; ++r) {
            const float rd = __shfl(iden[m], l4 * 4 + r);  // lane (l4*4+r) has q-col = l4*4+r
#pragma unroll
            for (int n2 = 0; n2 < 4; ++n2)
                out[(size_t)(qrow0 + wq + m * 16 + l4 * 4 + r) * 1024 + hcol + n2 * 16 + l15] =
                    (f16)(accv[m][n2][r] * rd);
        }
}

extern "C" void kernel_launch(void* const* d_in, const int* in_sizes, int n_in,
                              void* d_out, int out_size, void* d_ws, size_t ws_size,
                              hipStream_t stream) {
    const float* Xq = (const float*)d_in[0];
    const float* Xk = (const float*)d_in[1];
    const float* Xv = (const float*)d_in[2];
    const float* Wq = (const float*)d_in[3];
    const float* Wk = (const float*)d_in[4];
    const float* Wv = (const float*)d_in[5];
    const float* Wp = (const float*)d_in[6];
    const float* bp = (const float*)d_in[7];
    float* out = (float*)d_out;

    char* ws = (char*)d_ws;
    f16* W16 = (f16*)(ws);                      // 4M f16
    f16* X16 = (f16*)(ws + (8ull << 20));       // 12M f16: Xq16|Xk16|Xv16
    f16* vTb = (f16*)(ws + (8ull << 20));       // overlays Xq16 (dead after qk-gemm)
    f16* attnout = (f16*)(ws + (16ull << 20));  // overlays Xk16 (dead after vT-gemm)
    f16* Xv16 = (f16*)(ws + (24ull << 20));
    f16* qb = (f16*)(ws + (32ull << 20));       // qk out base (z-stride 4M f16)
    f16* kb = (f16*)(ws + (40ull << 20));
    // norms scratch in d_out head; written each launch before use, overwritten by final GEMM
    float* q2c2 = out;
    float* k2c2 = out + 65536;

    const float qsc = (float)(-2.0 * C2d);
    const float ns_q = (float)(1.0 / (4.0 * C2d));  // (q*-2C2)^2 * ns_q = C2*q^2
    const float ns_k = (float)C2d;

    cvt_all<<<8192, 256, 0, stream>>>(Xq, Xk, Xv, Wq, Wk, Wv, Wp, W16, X16);

    // fused q+k projection (z=0: q with -2*C2 prescale, z=1: k), norms in epilogue
    gemm_bt<true, false><<<dim3(16, 32, 2), 256, 0, stream>>>(
        X16, W16, qb, nullptr, nullptr, q2c2, qsc, 1.0f, ns_q, ns_k, 4096, 1024, 1024);

    // vT = Wv * Xv^T : [1024 d][4096 tok]
    gemm_bt<false, false><<<dim3(64, 8), 256, 0, stream>>>(
        W16 + 2 * (1u << 20), Xv16, vTb, nullptr, nullptr, nullptr, 1.0f, 1.0f, 0.f, 0.f, 1024, 4096, 1024);

    attn<<<dim3(8, 64), 256, 0, stream>>>(qb, kb, vTb, q2c2, k2c2, attnout);

    gemm_bt<false, true><<<dim3(16, 32), 256, 0, stream>>>(
        attnout, W16 + 3 * (1u << 20), nullptr, out, bp, nullptr, 1.0f, 1.0f, 0.f, 0.f, 4096, 1024, 1024);
}

// Round 7
// 121.741 us; speedup vs baseline: 1.6701x; 1.6701x over previous
//
#include <hip/hip_runtime.h>

// MultiHeadAttentionForViTDiscriminator: B=4, C=1024, D=1024, H=16, DH=64
// R7: R6 structure (swapped-operand QK on proven 16x16x32 + K-slot permutation,
//     in-register P, no Ps LDS) with the ONE fix: attn launch_bounds back to
//     (256,2) -- R6's (256,4) forced a 64-VGPR cap -> spill scratch traffic
//     (FETCH 12.6->177MB). R5 measured 108 VGPR at (256,2), no spill.
// Workspace (48 MB):
//   [0,8M)  W16 (Wq,Wk,Wv,Wp f16, contiguous 4M f16)
//   [8,32M) X16: Xq16,Xk16,Xv16; Xq16 slot -> vT after qk-gemm,
//           Xk16 slot -> attn_out after vT-gemm
//   [32,40M) qb (pre-scaled by -2*C2)   [40,48M) kb
//   norms q2c2/k2c2 (2 x 256KB f32) live in d_out's head (dead before final GEMM).

typedef _Float16 f16;
typedef __attribute__((ext_vector_type(2))) _Float16 f16x2;
typedef __attribute__((ext_vector_type(8))) _Float16 f16x8;
typedef __attribute__((ext_vector_type(4))) float f32x4;

#define MFMA16(a, b, c) __builtin_amdgcn_mfma_f32_16x16x32_f16((a), (b), (c), 0, 0, 0)

constexpr double LOG2E = 1.4426950408889634;
constexpr double C2d = 0.015625 * LOG2E * LOG2E;  // (DH^-0.5 * log2e)^2

#if __has_builtin(__builtin_amdgcn_exp2f)
#define EXP2F(x) __builtin_amdgcn_exp2f(x)
#else
#define EXP2F(x) exp2f(x)
#endif
#if __has_builtin(__builtin_amdgcn_sqrtf)
#define SQRTF(x) __builtin_amdgcn_sqrtf(x)
#else
#define SQRTF(x) sqrtf(x)
#endif

// Async global->LDS, 16B per lane (dest = wave-uniform base + lane*16).
__device__ __forceinline__ void stage16(const f16* g, f16* lds_base_uniform) {
#if __has_builtin(__builtin_amdgcn_global_load_lds)
    __builtin_amdgcn_global_load_lds((const __attribute__((address_space(1))) void*)g,
                                     (__attribute__((address_space(3))) void*)lds_base_uniform,
                                     16, 0, 0);
#else
    const int lane = threadIdx.x & 63;
    *(f16x8*)(lds_base_uniform + lane * 8) = *(const f16x8*)g;
#endif
}

// One conversion kernel for all fp32->fp16 inputs. 8192 blocks x 2048 elems = 16M.
__global__ __launch_bounds__(256) void cvt_all(const float* __restrict__ Xq,
                                               const float* __restrict__ Xk,
                                               const float* __restrict__ Xv,
                                               const float* __restrict__ Wq,
                                               const float* __restrict__ Wk,
                                               const float* __restrict__ Wv,
                                               const float* __restrict__ Wp,
                                               f16* __restrict__ W16,
                                               f16* __restrict__ X16) {
    const size_t idx = (size_t)blockIdx.x * 2048 + threadIdx.x * 8;
    const size_t M4 = 4ull << 20, M1 = 1ull << 20;
    const float* s;
    f16* d;
    if (idx < 3 * M4) {  // X region (12M)
        if (idx < M4) s = Xq + idx;
        else if (idx < 2 * M4) s = Xk + (idx - M4);
        else s = Xv + (idx - 2 * M4);
        d = X16 + idx;
    } else {  // W region (4M)
        size_t wi = idx - 3 * M4;
        if (wi < M1) s = Wq + wi;
        else if (wi < 2 * M1) s = Wk + (wi - M1);
        else if (wi < 3 * M1) s = Wv + (wi - 2 * M1);
        else s = Wp + (wi - 3 * M1);
        d = W16 + wi;
    }
    float4 a = *(const float4*)s;
    float4 b = *(const float4*)(s + 4);
    f16x8 o;
    o[0] = (f16)a.x; o[1] = (f16)a.y; o[2] = (f16)a.z; o[3] = (f16)a.w;
    o[4] = (f16)b.x; o[5] = (f16)b.y; o[6] = (f16)b.z; o[7] = (f16)b.w;
    *(f16x8*)d = o;
}

// C[M,N] = (A[M,K] * Bw[N,K]^T) * osc.  BM=128 BN=64 BK=64; 4 waves, wave tile 32x64.
// NORMS: emit per-row head-norms from the ROUNDED stored values.
// F32OUT: f32 out + bias.  blockIdx.z offsets A/Bw/Co/nrm (fused q/k launch).
template <bool NORMS, bool F32OUT>
__global__ __launch_bounds__(256, 2) void gemm_bt(const f16* __restrict__ A,
                                                  const f16* __restrict__ Bw,
                                                  f16* __restrict__ Co,
                                                  float* __restrict__ Cf,
                                                  const float* __restrict__ bias,
                                                  float* __restrict__ nrm,
                                                  float osc0, float osc1,
                                                  float ns0, float ns1,
                                                  int M, int N, int K) {
    __shared__ __attribute__((aligned(16))) f16 As[128 * 64];
    __shared__ __attribute__((aligned(16))) f16 Bs[64 * 64];
    const int tid = threadIdx.x;
    const int lane = tid & 63;
    const int w = tid >> 6;
    const int l15 = lane & 15, l4 = lane >> 4;
    const int z = blockIdx.z;
    A += (size_t)z * (4u << 20);
    Bw += (size_t)z * (1u << 20);
    Co += (size_t)z * (4u << 20);
    if (NORMS) nrm += (size_t)z * 65536;
    const float osc = z ? osc1 : osc0;
    const float nscale = z ? ns1 : ns0;
    const int wr = w * 32;
    // bijective XCD swizzle (nwg multiple of 8)
    const int nwg = gridDim.x * gridDim.y;
    const int f = blockIdx.y * gridDim.x + blockIdx.x;
    const int g = (f & 7) * (nwg >> 3) + (f >> 3);
    const int row0 = (g / gridDim.x) * 128;
    const int col0 = (g % gridDim.x) * 64;

    const int sr8 = lane >> 3;
    const int sc8 = (lane & 7) * 8;
    f32x4 acc[2][4] = {};

    for (int kt = 0; kt < K; kt += 64) {
        __syncthreads();
#pragma unroll
        for (int t = 0; t < 4; ++t)
            stage16(&A[(size_t)(row0 + w * 32 + t * 8 + sr8) * K + kt + sc8], &As[(w * 32 + t * 8) * 64]);
#pragma unroll
        for (int t = 0; t < 2; ++t)
            stage16(&Bw[(size_t)(col0 + w * 16 + t * 8 + sr8) * K + kt + sc8], &Bs[(w * 16 + t * 8) * 64]);
        __syncthreads();
#pragma unroll
        for (int ks = 0; ks < 2; ++ks) {
            f16x8 af[2], bf[4];
#pragma unroll
            for (int m = 0; m < 2; ++m)
                af[m] = *(const f16x8*)&As[(wr + m * 16 + l15) * 64 + ks * 32 + l4 * 8];
#pragma unroll
            for (int n = 0; n < 4; ++n)
                bf[n] = *(const f16x8*)&Bs[(n * 16 + l15) * 64 + ks * 32 + l4 * 8];
#pragma unroll
            for (int m = 0; m < 2; ++m)
#pragma unroll
                for (int n = 0; n < 4; ++n) acc[m][n] = MFMA16(af[m], bf[n], acc[m][n]);
        }
    }

    if (NORMS) {
        const int h = col0 >> 6;
#pragma unroll
        for (int m = 0; m < 2; ++m)
#pragma unroll
            for (int r = 0; r < 4; ++r) {
                float s = 0.f;
#pragma unroll
                for (int n = 0; n < 4; ++n) {
                    float v = (float)(f16)(acc[m][n][r] * osc);
                    s += v * v;
                }
                s += __shfl_xor(s, 1);
                s += __shfl_xor(s, 2);
                s += __shfl_xor(s, 4);
                s += __shfl_xor(s, 8);
                if (l15 == 0) {
                    int row = row0 + wr + m * 16 + l4 * 4 + r;
                    nrm[(size_t)((row >> 10) * 16 + h) * 1024 + (row & 1023)] = s * nscale;
                }
            }
    }

#pragma unroll
    for (int m = 0; m < 2; ++m)
#pragma unroll
        for (int n = 0; n < 4; ++n)
#pragma unroll
            for (int r = 0; r < 4; ++r) {
                int rr = row0 + wr + m * 16 + l4 * 4 + r;
                int cc = col0 + n * 16 + l15;
                if (F32OUT)
                    Cf[(size_t)rr * N + cc] = acc[m][n][r] + bias[cc];
                else
                    Co[(size_t)rr * N + cc] = (f16)(acc[m][n][r] * osc);
            }
}

// Distance attention. grid (8,64): 128 q-rows/block, 4 waves x 32 rows.
// Swapped QK (A=K,B=Q) + permuted K slots => in-register P; no Ps LDS.
// launch_bounds (256,2): measured-safe VGPR budget (R5: 108 VGPR, no spill).
__global__ __launch_bounds__(256, 2) void attn(const f16* __restrict__ qs,
                                               const f16* __restrict__ kb,
                                               const f16* __restrict__ vT,
                                               const float* __restrict__ q2c2,
                                               const float* __restrict__ k2c2,
                                               f16* __restrict__ out) {
    __shared__ __attribute__((aligned(16))) f16 Ks[128 * 64];  // permuted slots + XOR swizzle
    __shared__ __attribute__((aligned(16))) f16 Vs[64 * 128];  // XOR-swizzled
    __shared__ float k2tile[128];                              // linear (keyed by true k)
    const int tid = threadIdx.x;
    const int lane = tid & 63;
    const int w = tid >> 6;
    const int l15 = lane & 15, l4 = lane >> 4;
    // XCD remap: 8 bh per XCD -> K/V slices L2-resident
    const int fid = blockIdx.y * 8 + blockIdx.x;
    const int qt = (fid >> 3) & 7;
    const int bh = (fid & 7) * 8 + (fid >> 6);
    const int b = bh >> 4, h = bh & 15;
    const int wq = w * 32;
    const int hcol = h * 64;
    const int qrow0 = b * 1024 + qt * 128;
    const f16* vTh = vT + (size_t)hcol * 4096 + b * 1024;  // vT[d=1024][tok=4096]

    const int sr = tid >> 3, sc0 = (tid & 7) * 8;   // K staging (keys sr+i*32)
    const int vr = tid >> 4, vc0 = (tid & 15) * 8;  // V staging (rows vr+j*16)
    const int vsw = (vr & 7) << 3;
    const int fsw = (l15 & 7) << 3;                 // fragment-read swizzle (slot-row&7 = l15&7)

    // Q frags as B-operand (rows wq+m*16+l15), pre-scaled by -2*C2
    f16x8 bq[2][2];
#pragma unroll
    for (int m = 0; m < 2; ++m)
#pragma unroll
        for (int ks = 0; ks < 2; ++ks)
            bq[m][ks] = *(const f16x8*)&qs[(size_t)(qrow0 + wq + m * 16 + l15) * 1024 + hcol + ks * 32 + l4 * 8];
    // q2*C2 at lane-local q (col index l15)
    float q2m[2];
#pragma unroll
    for (int m = 0; m < 2; ++m) q2m[m] = q2c2[(size_t)bh * 1024 + qt * 128 + wq + m * 16 + l15];

    f32x4 accv[2][4] = {};
    float den[2] = {0.f, 0.f};

    f16x8 kreg[4], vreg[4];
    float k2reg = 0.f;
#define ISSUE_LOADS(KT)                                                                                      \
    {                                                                                                        \
        _Pragma("unroll") for (int i = 0; i < 4; ++i)                                                        \
            kreg[i] = *(const f16x8*)&kb[(size_t)(b * 1024 + (KT) * 128 + sr + i * 32) * 1024 + hcol + sc0]; \
        _Pragma("unroll") for (int j = 0; j < 4; ++j)                                                        \
            vreg[j] = *(const f16x8*)&vTh[(size_t)(vr + j * 16) * 4096 + (KT) * 128 + vc0];                  \
        k2reg = (tid < 128) ? k2c2[(size_t)bh * 1024 + (KT) * 128 + tid] : 0.f;                              \
    }

    ISSUE_LOADS(0)

    for (int kt = 0; kt < 8; ++kt) {
        __syncthreads();  // prev-tile readers done
        // K staging with slot permutation: key kap -> slot s so that QK D-rows
        // deliver PV A-frag k-order. s = ((kap>>5)&3)*32+((kap>>2)&1)*16+((kap>>3)&3)*4+(kap&3)
#pragma unroll
        for (int i = 0; i < 4; ++i) {
            const int kap = sr + i * 32;
            const int s = ((kap >> 5) & 3) * 32 + ((kap >> 2) & 1) * 16 + ((kap >> 3) & 3) * 4 + (kap & 3);
            *(f16x8*)&Ks[s * 64 + (sc0 ^ ((s & 7) << 3))] = kreg[i];
        }
#pragma unroll
        for (int j = 0; j < 4; ++j) *(f16x8*)&Vs[(vr + j * 16) * 128 + (vc0 ^ vsw)] = vreg[j];
        if (tid < 128) k2tile[tid] = k2reg;
        __syncthreads();
        if (kt < 7) ISSUE_LOADS(kt + 1)  // prefetch hides under compute

#pragma unroll
        for (int kk = 0; kk < 4; ++kk) {
            // QK for windows n=2kk, 2kk+1; assemble PV A-frag dwords in-register
            unsigned um[2][4];
#pragma unroll
            for (int half = 0; half < 2; ++half) {
                const int n = kk * 2 + half;
                f16x8 kf0 = *(const f16x8*)&Ks[(n * 16 + l15) * 64 + ((l4 * 8) ^ fsw)];
                f16x8 kf1 = *(const f16x8*)&Ks[(n * 16 + l15) * 64 + ((32 + l4 * 8) ^ fsw)];
                // true keys at this lane's D-rows: kk*32 + l4*8 + half*4 + r
                f32x4 k2q = *(const f32x4*)&k2tile[kk * 32 + l4 * 8 + half * 4];
#pragma unroll
                for (int m = 0; m < 2; ++m) {
                    f32x4 c0;
#pragma unroll
                    for (int r = 0; r < 4; ++r) c0[r] = q2m[m] + k2q[r];
                    f32x4 st = MFMA16(kf0, bq[m][0], c0);
                    st = MFMA16(kf1, bq[m][1], st);
                    float p0 = EXP2F(SQRTF(fmaxf(st[0], 0.f)));
                    float p1 = EXP2F(SQRTF(fmaxf(st[1], 0.f)));
                    float p2 = EXP2F(SQRTF(fmaxf(st[2], 0.f)));
                    float p3 = EXP2F(SQRTF(fmaxf(st[3], 0.f)));
                    den[m] += (p0 + p1) + (p2 + p3);
                    f16x2 lo = {(f16)p0, (f16)p1};
                    f16x2 hi = {(f16)p2, (f16)p3};
                    um[m][half * 2] = __builtin_bit_cast(unsigned, lo);
                    um[m][half * 2 + 1] = __builtin_bit_cast(unsigned, hi);
                }
            }
            f16x8 ap[2];
#pragma unroll
            for (int m = 0; m < 2; ++m) {
                uint4 u = {um[m][0], um[m][1], um[m][2], um[m][3]};
                ap[m] = __builtin_bit_cast(f16x8, u);
            }
            // PV for this kk (B-operand: V^T rows = d = n2*16+l15)
#pragma unroll
            for (int n2 = 0; n2 < 4; ++n2) {
                f16x8 bv = *(const f16x8*)&Vs[(n2 * 16 + l15) * 128 + ((kk * 32 + l4 * 8) ^ fsw)];
#pragma unroll
                for (int m = 0; m < 2; ++m) accv[m][n2] = MFMA16(ap[m], bv, accv[m][n2]);
            }
        }
    }

    // den: reduce across l4 groups (q = wq+m*16+l15 fixed per lane per m)
    float iden[2];
#pragma unroll
    for (int m = 0; m < 2; ++m) {
        float d = den[m];
        d += __shfl_xor(d, 16);
        d += __shfl_xor(d, 32);
        iden[m] = 1.0f / d;
    }
#pragma unroll
    for (int m = 0; m < 2; ++m)
#pragma unroll
        for (int r = 0; r < 4; ++r) {
            const float rd = __shfl(iden[m], l4 * 4 + r);  // lane (l4*4+r) has q-col = l4*4+r
#pragma unroll
            for (int n2 = 0; n2 < 4; ++n2)
                out[(size_t)(qrow0 + wq + m * 16 + l4 * 4 + r) * 1024 + hcol + n2 * 16 + l15] =
                    (f16)(accv[m][n2][r] * rd);
        }
}

extern "C" void kernel_launch(void* const* d_in, const int* in_sizes, int n_in,
                              void* d_out, int out_size, void* d_ws, size_t ws_size,
                              hipStream_t stream) {
    const float* Xq = (const float*)d_in[0];
    const float* Xk = (const float*)d_in[1];
    const float* Xv = (const float*)d_in[2];
    const float* Wq = (const float*)d_in[3];
    const float* Wk = (const float*)d_in[4];
    const float* Wv = (const float*)d_in[5];
    const float* Wp = (const float*)d_in[6];
    const float* bp = (const float*)d_in[7];
    float* out = (float*)d_out;

    char* ws = (char*)d_ws;
    f16* W16 = (f16*)(ws);                      // 4M f16
    f16* X16 = (f16*)(ws + (8ull << 20));       // 12M f16: Xq16|Xk16|Xv16
    f16* vTb = (f16*)(ws + (8ull << 20));       // overlays Xq16 (dead after qk-gemm)
    f16* attnout = (f16*)(ws + (16ull << 20));  // overlays Xk16 (dead after vT-gemm)
    f16* Xv16 = (f16*)(ws + (24ull << 20));
    f16* qb = (f16*)(ws + (32ull << 20));       // qk out base (z-stride 4M f16)
    f16* kb = (f16*)(ws + (40ull << 20));
    // norms scratch in d_out head; written each launch before use, overwritten by final GEMM
    float* q2c2 = out;
    float* k2c2 = out + 65536;

    const float qsc = (float)(-2.0 * C2d);
    const float ns_q = (float)(1.0 / (4.0 * C2d));  // (q*-2C2)^2 * ns_q = C2*q^2
    const float ns_k = (float)C2d;

    cvt_all<<<8192, 256, 0, stream>>>(Xq, Xk, Xv, Wq, Wk, Wv, Wp, W16, X16);

    // fused q+k projection (z=0: q with -2*C2 prescale, z=1: k), norms in epilogue
    gemm_bt<true, false><<<dim3(16, 32, 2), 256, 0, stream>>>(
        X16, W16, qb, nullptr, nullptr, q2c2, qsc, 1.0f, ns_q, ns_k, 4096, 1024, 1024);

    // vT = Wv * Xv^T : [1024 d][4096 tok]
    gemm_bt<false, false><<<dim3(64, 8), 256, 0, stream>>>(
        W16 + 2 * (1u << 20), Xv16, vTb, nullptr, nullptr, nullptr, 1.0f, 1.0f, 0.f, 0.f, 1024, 4096, 1024);

    attn<<<dim3(8, 64), 256, 0, stream>>>(qb, kb, vTb, q2c2, k2c2, attnout);

    gemm_bt<false, true><<<dim3(16, 32), 256, 0, stream>>>(
        attnout, W16 + 3 * (1u << 20), nullptr, out, bp, nullptr, 1.0f, 1.0f, 0.f, 0.f, 4096, 1024, 1024);
}